// Round 4
// baseline (69477.710 us; speedup 1.0000x reference)
//
#include <hip/hip_runtime.h>
#include <stdint.h>

#define TT    8192
#define EMBD  128
#define HID   256
#define G4    1024      // 4*HID
#define NTAGS 17
#define NBLK  16        // recurrence participants (all on one XCD)
#define SH    16        // HID / NBLK
#define QW    68        // padded LDS stride per k-quarter (conflict-free)
#define REG_GRID 256    // registration grid for lstm

typedef unsigned int u32;

__device__ __forceinline__ float sigf(float x) { return 1.f / (1.f + __expf(-x)); }
__device__ __forceinline__ float tanhf_fast(float x) {
    x = fminf(15.f, fmaxf(-15.f, x));
    float a = __expf(2.f * x);
    return (a - 1.f) / (a + 1.f);
}

// sc0 = L1-bypass, serviced by the XCD-shared L2 (~200 cy). Valid for
// same-XCD communication only — which registration guarantees.
__device__ __forceinline__ u32 load_u32_sc0(const u32* p) {
    u32 v;
    asm volatile("global_load_dword %0, %1, off sc0\n\ts_waitcnt vmcnt(0)"
                 : "=v"(v) : "v"(p) : "memory");
    return v;
}
__device__ __forceinline__ void store_u32_sc0(u32* p, u32 v) {
    asm volatile("global_store_dword %0, %1, off sc0" :: "v"(p), "v"(v) : "memory");
}

// ---------------------------------------------------------------------------
// Kernel A: xg[t][j] = dot(emb[tok[t]], W_ih[j]) + b_ih[j] + b_hh[j]
// Block 0 also inits the registration pool/winner and the agent mirror.
// ---------------------------------------------------------------------------
__global__ __launch_bounds__(256) void xg_kernel(
    const int* __restrict__ tok, const float* __restrict__ emb,
    const float* __restrict__ Wih, const float* __restrict__ bih,
    const float* __restrict__ bhh, float* __restrict__ xg,
    int* __restrict__ pool, int* __restrict__ winner, u32* __restrict__ hx2)
{
    __shared__ __align__(16) float es[4][EMBD];
    const int tid = threadIdx.x;
    const int t0  = blockIdx.x * 4;

    if (blockIdx.x == 0) {
        if (tid < 16) pool[tid] = 0;
        if (tid == 16) *winner = -1;
        if (tid < 2 * HID + 32) hx2[tid] = 0u;   // mirror (2*256) + slack
    }

    for (int p = tid; p < 4 * EMBD; p += 256) {
        const int tt = p >> 7, k = p & 127;
        es[tt][k] = emb[(long)tok[t0 + tt] * EMBD + k];
    }
    __syncthreads();

#pragma unroll
    for (int q = 0; q < 4; ++q) {
        const int j = q * 256 + tid;
        const float4* wr = (const float4*)(Wih + (long)j * EMBD);
        float a0 = 0.f, a1 = 0.f, a2 = 0.f, a3 = 0.f;
#pragma unroll 8
        for (int k4 = 0; k4 < EMBD / 4; ++k4) {
            const float4 w  = wr[k4];
            const float4 e0 = ((const float4*)es[0])[k4];
            const float4 e1 = ((const float4*)es[1])[k4];
            const float4 e2 = ((const float4*)es[2])[k4];
            const float4 e3 = ((const float4*)es[3])[k4];
            a0 += w.x*e0.x + w.y*e0.y + w.z*e0.z + w.w*e0.w;
            a1 += w.x*e1.x + w.y*e1.y + w.z*e1.z + w.w*e1.w;
            a2 += w.x*e2.x + w.y*e2.y + w.z*e2.z + w.w*e2.w;
            a3 += w.x*e3.x + w.y*e3.y + w.z*e3.z + w.w*e3.w;
        }
        const float bb = bih[j] + bhh[j];
        xg[(long)(t0 + 0) * G4 + j] = a0 + bb;
        xg[(long)(t0 + 1) * G4 + j] = a1 + bb;
        xg[(long)(t0 + 2) * G4 + j] = a2 + bb;
        xg[(long)(t0 + 3) * G4 + j] = a3 + bb;
    }
}

// ---------------------------------------------------------------------------
// Kernel B: LSTM recurrence, NBLK=16 working blocks ON ONE XCD.
// Registration: 256 blocks read HW_REG_XCC_ID (id 20, measured to return
// 0..7), take a slot in pool[xcc]; the 16th registrant CASes its XCD as
// winner; blocks not on the winner exit. Pigeonhole (256 regs / 8 ids)
// guarantees a winner; registration never blocks, so no deadlock.
//
// Exchange per step: producer packs ((s+1)<<16)|bf16(h) and stores it
//   (a) sc0 -> shared L2 (fast path, full history in hx), and
//   (b) agent-scope relaxed -> 2-slot mirror hx2 (Round-3-proven fallback).
// Consumers spin on (a) with sc0 loads; every 64 misses they also check
// (b). Mirror slot for step s+1 is only overwritten at step s+3, which
// transitively requires every block consumed s+1 -> fallback is race-free.
// ---------------------------------------------------------------------------
__global__ __launch_bounds__(256, 2) void lstm_kernel(
    const float* __restrict__ Whh, const float* __restrict__ xg,
    u32* __restrict__ hx, u32* __restrict__ hx2,
    int* __restrict__ pool, int* __restrict__ winner)
{
    const int tid = threadIdx.x;
    __shared__ int s_b;
    if (tid == 0) {
        const u32 xcc = __builtin_amdgcn_s_getreg(20 | (31 << 11)) & 0xFu;
        int b = -1;
        const int slot = atomicAdd(&pool[xcc], 1);
        if (slot < NBLK) {
            if (slot == NBLK - 1) atomicCAS(winner, -1, (int)xcc);
            int w;
            while ((w = __hip_atomic_load(winner, __ATOMIC_RELAXED,
                                          __HIP_MEMORY_SCOPE_AGENT)) == -1)
                __builtin_amdgcn_s_sleep(8);
            if (w == (int)xcc) b = slot;
        }
        s_b = b;
    }
    __syncthreads();
    const int b = s_b;
    if (b < 0) return;                 // not part of the winning XCD's 16

    const int w   = tid >> 6;
    const int L   = tid & 63;
    const int g   = L >> 4;
    const int l15 = L & 15;
    const int hi  = l15 >> 2;
    const int q   = L & 3;
    const int row = g * HID + b * SH + w * 4 + hi;

    // register-resident W_hh slice: 64 floats/thread
    float4 wv[16];
    const float4* wsrc = (const float4*)(Whh + (long)row * HID + q * 64);
#pragma unroll
    for (int j = 0; j < 16; ++j) wv[j] = wsrc[j];

    __shared__ __align__(16) float hlds[2][4 * QW];
    for (int i = tid; i < 4 * QW; i += 256) hlds[0][i] = 0.f;   // h_0 = 0
    __syncthreads();

    float c_reg = 0.f;
    const bool leader = (g == 0) && (q == 0);
    const int  gidx   = b * SH + w * 4 + hi;
    const int  myslot = (tid >> 6) * QW + (tid & 63);

    const float* xgp = xg + row;
    float xg0 = xgp[0];
    float xg1 = xgp[G4];               // prefetch may run 2 rows past xg end
                                       // (lands in hx region: valid, unused)
    auto step = [&](int s, float xgv) {
        const int cur = s & 1;
        const float* hb = &hlds[cur][q * QW];
        float p0 = 0.f, p1 = 0.f, p2 = 0.f, p3 = 0.f;
#pragma unroll
        for (int j = 0; j < 16; ++j) {
            const float4 hv = *(const float4*)(hb + j * 4);
            p0 += wv[j].x * hv.x; p1 += wv[j].y * hv.y;
            p2 += wv[j].z * hv.z; p3 += wv[j].w * hv.w;
        }
        float p = (p0 + p1) + (p2 + p3);
        p += __shfl_xor(p, 1, 64);
        p += __shfl_xor(p, 2, 64);
        const float pre = p + xgv;
        const float vf = __shfl(pre, 16 + l15, 64);
        const float vg = __shfl(pre, 32 + l15, 64);
        const float vo = __shfl(pre, 48 + l15, 64);
        if (leader) {
            const float i_ = sigf(pre);
            const float f_ = sigf(vf);
            const float g_ = tanhf_fast(vg);
            const float o_ = sigf(vo);
            c_reg = f_ * c_reg + i_ * g_;
            const float hn = o_ * tanhf_fast(c_reg);
            const u32 hb32 = __float_as_uint(hn);
            const u32 rb   = (hb32 + 0x7FFFu + ((hb32 >> 16) & 1u)) >> 16;
            const u32 word = ((u32)(s + 1) << 16) | rb;
            store_u32_sc0(&hx[(long)(s + 1) * HID + gidx], word);   // fast path
            __hip_atomic_store(&hx2[((s + 1) & 1) * HID + gidx], word,
                               __ATOMIC_RELAXED, __HIP_MEMORY_SCOPE_AGENT);
            hlds[cur ^ 1][(gidx >> 6) * QW + (gidx & 63)] =
                __uint_as_float(rb << 16);
        }
        if ((tid >> 4) != b) {
            const u32 want = (u32)(s + 1) << 16;
            u32* wp  = &hx[(long)(s + 1) * HID + tid];
            u32* wp2 = &hx2[((s + 1) & 1) * HID + tid];
            u32 u; int spins = 0;
            for (;;) {
                u = load_u32_sc0(wp);
                if ((u & 0xFFFF0000u) == want) break;
                if ((++spins & 63) == 0) {
                    u = __hip_atomic_load(wp2, __ATOMIC_RELAXED,
                                          __HIP_MEMORY_SCOPE_AGENT);
                    if ((u & 0xFFFF0000u) == want) break;
                }
            }
            hlds[cur ^ 1][myslot] = __uint_as_float(u << 16);
        }
        __syncthreads();
    };

    for (int s = 0; s < TT; s += 2) {
        const float xgn0 = xgp[(long)(s + 2) * G4];
        step(s, xg0);
        const float xgn1 = xgp[(long)(s + 3) * G4];
        step(s + 1, xg1);
        xg0 = xgn0; xg1 = xgn1;
    }
}

// ---------------------------------------------------------------------------
// Kernel C: tag logits + log_softmax; unpacks bf16 h from tagged words.
// ---------------------------------------------------------------------------
__global__ __launch_bounds__(64) void out_kernel(
    const u32* __restrict__ hx, const float* __restrict__ Wout,
    const float* __restrict__ bout, float* __restrict__ out)
{
    const int t   = blockIdx.x;
    const int tid = threadIdx.x;
    __shared__ __align__(16) float hs[HID];
    __shared__ float lg[NTAGS];

    const uint4 uu = ((const uint4*)(hx + (long)(t + 1) * HID))[tid];
    hs[tid * 4 + 0] = __uint_as_float(uu.x << 16);
    hs[tid * 4 + 1] = __uint_as_float(uu.y << 16);
    hs[tid * 4 + 2] = __uint_as_float(uu.z << 16);
    hs[tid * 4 + 3] = __uint_as_float(uu.w << 16);
    __syncthreads();

    if (tid < NTAGS) {
        const float4* wr = (const float4*)(Wout + (long)tid * HID);
        float p = 0.f;
#pragma unroll 8
        for (int qq = 0; qq < HID / 4; ++qq) {
            const float4 w = wr[qq];
            const float4 h = ((const float4*)hs)[qq];
            p += w.x*h.x + w.y*h.y + w.z*h.z + w.w*h.w;
        }
        lg[tid] = p + bout[tid];
    }
    __syncthreads();

    if (tid < NTAGS) {
        float m = -1e30f;
        for (int gg = 0; gg < NTAGS; ++gg) m = fmaxf(m, lg[gg]);
        float ss = 0.f;
        for (int gg = 0; gg < NTAGS; ++gg) ss += __expf(lg[gg] - m);
        out[(long)t * NTAGS + tid] = lg[tid] - (m + __logf(ss));
    }
}

// ---------------------------------------------------------------------------
// ws layout (total 41,948,424 B — under Round 1's proven 41,976,832):
//   xg   : 33,554,432 B
//   hx   :  8,389,632 B   (8193 * 256 tagged words)
//   hx2  :      2,176 B   (2 * 256 mirror + slack)
//   pool :         64 B   (16 ints)
//   winner:         4 B
// ---------------------------------------------------------------------------
extern "C" void kernel_launch(void* const* d_in, const int* in_sizes, int n_in,
                              void* d_out, int out_size, void* d_ws, size_t ws_size,
                              hipStream_t stream)
{
    const int*   tok  = (const int*)  d_in[0];
    const float* emb  = (const float*)d_in[1];
    const float* Wih  = (const float*)d_in[2];
    const float* Whh  = (const float*)d_in[3];
    const float* bih  = (const float*)d_in[4];
    const float* bhh  = (const float*)d_in[5];
    const float* Wout = (const float*)d_in[6];
    const float* bout = (const float*)d_in[7];
    float* out = (float*)d_out;

    char* ws = (char*)d_ws;
    float* xg     = (float*)(ws);
    u32*   hx     = (u32*)  (ws + 33554432UL);
    u32*   hx2    = (u32*)  (ws + 33554432UL + 8389632UL);
    int*   pool   = (int*)  (ws + 33554432UL + 8389632UL + 2176UL);
    int*   winner = (int*)  (ws + 33554432UL + 8389632UL + 2176UL + 64UL);

    xg_kernel  <<<TT / 4,   256, 0, stream>>>(tok, emb, Wih, bih, bhh, xg,
                                              pool, winner, hx2);
    lstm_kernel<<<REG_GRID, 256, 0, stream>>>(Whh, xg, hx, hx2, pool, winner);
    out_kernel <<<TT,       64,  0, stream>>>(hx, Wout, bout, out);
}

// Round 5
// 17968.674 us; speedup vs baseline: 3.8666x; 3.8666x over previous
//
#include <hip/hip_runtime.h>
#include <stdint.h>

#define TT    8192
#define EMBD  128
#define HID   256
#define G4    1024      // 4*HID
#define NTAGS 17
#define NBLK  16        // recurrence participants (goal: all on one XCD)
#define SH    16        // HID / NBLK
#define QW    68        // padded LDS stride per k-quarter (conflict-free)
#define REG_GRID 256    // registration grid for lstm

typedef unsigned int u32;

__device__ __forceinline__ float sigf(float x) { return 1.f / (1.f + __expf(-x)); }
__device__ __forceinline__ float tanhf_fast(float x) {
    x = fminf(15.f, fmaxf(-15.f, x));
    float a = __expf(2.f * x);
    return (a - 1.f) / (a + 1.f);
}

// sc0 = L1-bypass, serviced by the XCD-shared L2. Only meaningful for
// same-XCD communication — correctness never depends on it (mirror fallback).
__device__ __forceinline__ u32 load_u32_sc0(const u32* p) {
    u32 v;
    asm volatile("global_load_dword %0, %1, off sc0\n\ts_waitcnt vmcnt(0)"
                 : "=v"(v) : "v"(p) : "memory");
    return v;
}
__device__ __forceinline__ void store_u32_sc0(u32* p, u32 v) {
    asm volatile("global_store_dword %0, %1, off sc0" :: "v"(p), "v"(v) : "memory");
}

// ---------------------------------------------------------------------------
// Kernel A: xg[t][j] = dot(emb[tok[t]], W_ih[j]) + b_ih[j] + b_hh[j]
// Block 0 also inits the registration pool/winner and the agent mirror.
// ---------------------------------------------------------------------------
__global__ __launch_bounds__(256) void xg_kernel(
    const int* __restrict__ tok, const float* __restrict__ emb,
    const float* __restrict__ Wih, const float* __restrict__ bih,
    const float* __restrict__ bhh, float* __restrict__ xg,
    int* __restrict__ pool, int* __restrict__ winner, u32* __restrict__ hx2)
{
    __shared__ __align__(16) float es[4][EMBD];
    const int tid = threadIdx.x;
    const int t0  = blockIdx.x * 4;

    if (blockIdx.x == 0) {
        if (tid < 16) pool[tid] = 0;
        if (tid == 16) *winner = -1;
        if (tid < 2 * HID + 32) hx2[tid] = 0u;   // mirror slots + slack
    }

    for (int p = tid; p < 4 * EMBD; p += 256) {
        const int tt = p >> 7, k = p & 127;
        es[tt][k] = emb[(long)tok[t0 + tt] * EMBD + k];
    }
    __syncthreads();

#pragma unroll
    for (int q = 0; q < 4; ++q) {
        const int j = q * 256 + tid;
        const float4* wr = (const float4*)(Wih + (long)j * EMBD);
        float a0 = 0.f, a1 = 0.f, a2 = 0.f, a3 = 0.f;
#pragma unroll 8
        for (int k4 = 0; k4 < EMBD / 4; ++k4) {
            const float4 w  = wr[k4];
            const float4 e0 = ((const float4*)es[0])[k4];
            const float4 e1 = ((const float4*)es[1])[k4];
            const float4 e2 = ((const float4*)es[2])[k4];
            const float4 e3 = ((const float4*)es[3])[k4];
            a0 += w.x*e0.x + w.y*e0.y + w.z*e0.z + w.w*e0.w;
            a1 += w.x*e1.x + w.y*e1.y + w.z*e1.z + w.w*e1.w;
            a2 += w.x*e2.x + w.y*e2.y + w.z*e2.z + w.w*e2.w;
            a3 += w.x*e3.x + w.y*e3.y + w.z*e3.z + w.w*e3.w;
        }
        const float bb = bih[j] + bhh[j];
        xg[(long)(t0 + 0) * G4 + j] = a0 + bb;
        xg[(long)(t0 + 1) * G4 + j] = a1 + bb;
        xg[(long)(t0 + 2) * G4 + j] = a2 + bb;
        xg[(long)(t0 + 3) * G4 + j] = a3 + bb;
    }
}

// ---------------------------------------------------------------------------
// Kernel B: LSTM recurrence, NBLK=16 working blocks, target: one XCD.
// Registration: 256 blocks read HW_REG_XCC_ID with the exact 4-bit window
// (id=20, offset=0, size=4 -> imm 6164; R4's 32-bit-wide read is the prime
// suspect for returning 0 and scattering the winners across XCDs).
// Pigeonhole (256 blocks / <=16 buckets) guarantees a winner; registration
// never blocks -> no deadlock.
//
// Exchange per step: producer packs ((s+1)<<16)|bf16(h) and dual-publishes:
//   (a) sc0 -> shared L2 (fast path, full history in hx)
//   (b) agent-relaxed -> 2-slot mirror hx2 (Round-3-proven fallback; slot
//       for h_{s+1} provably not overwritten until all blocks consumed it)
// Consumers: adaptive sc0 spin budget (12 normally; 2 right after a
// fallback, restored on success) then mirror polling. Worst case ~= R3.
// ---------------------------------------------------------------------------
__global__ __launch_bounds__(256) void lstm_kernel(
    const float* __restrict__ Whh, const float* __restrict__ xg,
    u32* __restrict__ hx, u32* __restrict__ hx2,
    int* __restrict__ pool, int* __restrict__ winner)
{
    const int tid = threadIdx.x;
    __shared__ int s_b;
    if (tid == 0) {
        const u32 xcc = __builtin_amdgcn_s_getreg(20 | (3 << 11)) & 0xFu; // 4-bit read
        int b = -1;
        const int slot = atomicAdd(&pool[xcc], 1);
        if (slot < NBLK) {
            if (slot == NBLK - 1) atomicCAS(winner, -1, (int)xcc);
            int w;
            while ((w = __hip_atomic_load(winner, __ATOMIC_RELAXED,
                                          __HIP_MEMORY_SCOPE_AGENT)) == -1)
                __builtin_amdgcn_s_sleep(8);
            if (w == (int)xcc) b = slot;
        }
        s_b = b;
    }
    __syncthreads();
    const int b = s_b;
    if (b < 0) return;                 // not part of the winning 16

    const int w   = tid >> 6;
    const int L   = tid & 63;
    const int g   = L >> 4;
    const int l15 = L & 15;
    const int hi  = l15 >> 2;
    const int q   = L & 3;
    const int row = g * HID + b * SH + w * 4 + hi;

    // register-resident W_hh slice: 64 floats/thread, PINNED via asm barrier
    // (R3/R4 VGPR_Count=52/56 proved the compiler rematerialized these loads
    //  from L2 every step — directly on the critical path)
    float4 wv[16];
    const float4* wsrc = (const float4*)(Whh + (long)row * HID + q * 64);
#pragma unroll
    for (int j = 0; j < 16; ++j) wv[j] = wsrc[j];
#pragma unroll
    for (int j = 0; j < 16; ++j)
        asm volatile("" : "+v"(wv[j].x), "+v"(wv[j].y), "+v"(wv[j].z), "+v"(wv[j].w));

    __shared__ __align__(16) float hlds[2][4 * QW];
    for (int i = tid; i < 4 * QW; i += 256) hlds[0][i] = 0.f;   // h_0 = 0
    __syncthreads();

    float c_reg = 0.f;
    int   kbud  = 12;                  // adaptive sc0 spin budget
    const bool leader = (g == 0) && (q == 0);
    const int  gidx   = b * SH + w * 4 + hi;
    const int  myslot = (tid >> 6) * QW + (tid & 63);

    const float* xgp = xg + row;
    float xg0 = xgp[0];
    float xg1 = xgp[G4];               // may prefetch past xg end into hx: benign

    auto step = [&](int s, float xgv) {
        const int cur = s & 1;
        const float* hb = &hlds[cur][q * QW];
        float p0 = 0.f, p1 = 0.f, p2 = 0.f, p3 = 0.f;
#pragma unroll
        for (int j = 0; j < 16; ++j) {
            const float4 hv = *(const float4*)(hb + j * 4);
            p0 += wv[j].x * hv.x; p1 += wv[j].y * hv.y;
            p2 += wv[j].z * hv.z; p3 += wv[j].w * hv.w;
        }
        float p = (p0 + p1) + (p2 + p3);
        p += __shfl_xor(p, 1, 64);
        p += __shfl_xor(p, 2, 64);
        const float pre = p + xgv;
        const float vf = __shfl(pre, 16 + l15, 64);
        const float vg = __shfl(pre, 32 + l15, 64);
        const float vo = __shfl(pre, 48 + l15, 64);
        if (leader) {
            const float i_ = sigf(pre);
            const float f_ = sigf(vf);
            const float g_ = tanhf_fast(vg);
            const float o_ = sigf(vo);
            c_reg = f_ * c_reg + i_ * g_;
            const float hn = o_ * tanhf_fast(c_reg);
            const u32 hb32 = __float_as_uint(hn);
            const u32 rb   = (hb32 + 0x7FFFu + ((hb32 >> 16) & 1u)) >> 16;
            const u32 word = ((u32)(s + 1) << 16) | rb;
            store_u32_sc0(&hx[(long)(s + 1) * HID + gidx], word);   // fast path
            __hip_atomic_store(&hx2[((s + 1) & 1) * HID + gidx], word,
                               __ATOMIC_RELAXED, __HIP_MEMORY_SCOPE_AGENT);
            hlds[cur ^ 1][(gidx >> 6) * QW + (gidx & 63)] =
                __uint_as_float(rb << 16);
        }
        if ((tid >> 4) != b) {
            const u32 want = (u32)(s + 1) << 16;
            u32* wp  = &hx[(long)(s + 1) * HID + tid];
            u32* wp2 = &hx2[((s + 1) & 1) * HID + tid];
            u32 u; bool fast = false;
            for (int it = 0; it < kbud; ++it) {
                u = load_u32_sc0(wp);
                if ((u & 0xFFFF0000u) == want) { fast = true; break; }
            }
            if (!fast) {
                do { u = __hip_atomic_load(wp2, __ATOMIC_RELAXED,
                                           __HIP_MEMORY_SCOPE_AGENT); }
                while ((u & 0xFFFF0000u) != want);
                kbud = 2;              // placement looks broken: probe lightly
            } else {
                kbud = 12;             // fast path healthy: full budget
            }
            hlds[cur ^ 1][myslot] = __uint_as_float(u << 16);
        }
        __syncthreads();
    };

    for (int s = 0; s < TT; s += 2) {
        const float xgn0 = xgp[(long)(s + 2) * G4];
        step(s, xg0);
        const float xgn1 = xgp[(long)(s + 3) * G4];
        step(s + 1, xg1);
        xg0 = xgn0; xg1 = xgn1;
    }
}

// ---------------------------------------------------------------------------
// Kernel C: tag logits + log_softmax; unpacks bf16 h from tagged words.
// ---------------------------------------------------------------------------
__global__ __launch_bounds__(64) void out_kernel(
    const u32* __restrict__ hx, const float* __restrict__ Wout,
    const float* __restrict__ bout, float* __restrict__ out)
{
    const int t   = blockIdx.x;
    const int tid = threadIdx.x;
    __shared__ __align__(16) float hs[HID];
    __shared__ float lg[NTAGS];

    const uint4 uu = ((const uint4*)(hx + (long)(t + 1) * HID))[tid];
    hs[tid * 4 + 0] = __uint_as_float(uu.x << 16);
    hs[tid * 4 + 1] = __uint_as_float(uu.y << 16);
    hs[tid * 4 + 2] = __uint_as_float(uu.z << 16);
    hs[tid * 4 + 3] = __uint_as_float(uu.w << 16);
    __syncthreads();

    if (tid < NTAGS) {
        const float4* wr = (const float4*)(Wout + (long)tid * HID);
        float p = 0.f;
#pragma unroll 8
        for (int qq = 0; qq < HID / 4; ++qq) {
            const float4 w = wr[qq];
            const float4 h = ((const float4*)hs)[qq];
            p += w.x*h.x + w.y*h.y + w.z*h.z + w.w*h.w;
        }
        lg[tid] = p + bout[tid];
    }
    __syncthreads();

    if (tid < NTAGS) {
        float m = -1e30f;
        for (int gg = 0; gg < NTAGS; ++gg) m = fmaxf(m, lg[gg]);
        float ss = 0.f;
        for (int gg = 0; gg < NTAGS; ++gg) ss += __expf(lg[gg] - m);
        out[(long)t * NTAGS + tid] = lg[tid] - (m + __logf(ss));
    }
}

// ---------------------------------------------------------------------------
// ws layout (total 41,948,424 B — R4-proven to fit):
//   xg     : 33,554,432 B
//   hx     :  8,389,632 B   (8193 * 256 tagged words)
//   hx2    :      2,176 B   (2 * 256 mirror + slack)
//   pool   :         64 B
//   winner :          4 B
// ---------------------------------------------------------------------------
extern "C" void kernel_launch(void* const* d_in, const int* in_sizes, int n_in,
                              void* d_out, int out_size, void* d_ws, size_t ws_size,
                              hipStream_t stream)
{
    const int*   tok  = (const int*)  d_in[0];
    const float* emb  = (const float*)d_in[1];
    const float* Wih  = (const float*)d_in[2];
    const float* Whh  = (const float*)d_in[3];
    const float* bih  = (const float*)d_in[4];
    const float* bhh  = (const float*)d_in[5];
    const float* Wout = (const float*)d_in[6];
    const float* bout = (const float*)d_in[7];
    float* out = (float*)d_out;

    char* ws = (char*)d_ws;
    float* xg     = (float*)(ws);
    u32*   hx     = (u32*)  (ws + 33554432UL);
    u32*   hx2    = (u32*)  (ws + 33554432UL + 8389632UL);
    int*   pool   = (int*)  (ws + 33554432UL + 8389632UL + 2176UL);
    int*   winner = (int*)  (ws + 33554432UL + 8389632UL + 2176UL + 64UL);

    xg_kernel  <<<TT / 4,   256, 0, stream>>>(tok, emb, Wih, bih, bhh, xg,
                                              pool, winner, hx2);
    lstm_kernel<<<REG_GRID, 256, 0, stream>>>(Whh, xg, hx, hx2, pool, winner);
    out_kernel <<<TT,       64,  0, stream>>>(hx, Wout, bout, out);
}

// Round 6
// 16816.388 us; speedup vs baseline: 4.1315x; 1.0685x over previous
//
#include <hip/hip_runtime.h>
#include <stdint.h>

#define TT    8192
#define EMBD  128
#define HID   256
#define G4    1024      // 4*HID
#define NTAGS 17
#define NBLK  16        // recurrence participants (goal: all on one XCD)
#define SH    16        // HID / NBLK
#define QW    68        // padded LDS stride per k-quarter (conflict-free)
#define REG_GRID 256    // registration grid for lstm

typedef unsigned int u32;

__device__ __forceinline__ float sigf(float x) { return 1.f / (1.f + __expf(-x)); }
__device__ __forceinline__ float tanhf_fast(float x) {
    x = fminf(15.f, fmaxf(-15.f, x));
    float a = __expf(2.f * x);
    return (a - 1.f) / (a + 1.f);
}

// sc0 = L1-bypass, serviced by the XCD-shared L2. Only useful for same-XCD
// communication — correctness never depends on it (agent mirror fallback).
__device__ __forceinline__ u32 load_u32_sc0(const u32* p) {
    u32 v;
    asm volatile("global_load_dword %0, %1, off sc0\n\ts_waitcnt vmcnt(0)"
                 : "=v"(v) : "v"(p) : "memory");
    return v;
}
__device__ __forceinline__ void store_u32_sc0(u32* p, u32 v) {
    asm volatile("global_store_dword %0, %1, off sc0" :: "v"(p), "v"(v) : "memory");
}

// ---------------------------------------------------------------------------
// Kernel A: xg[t][j] = dot(emb[tok[t]], W_ih[j]) + b_ih[j] + b_hh[j]
// Block 0 also inits the registration pool/winner and the agent mirror.
// ---------------------------------------------------------------------------
__global__ __launch_bounds__(256) void xg_kernel(
    const int* __restrict__ tok, const float* __restrict__ emb,
    const float* __restrict__ Wih, const float* __restrict__ bih,
    const float* __restrict__ bhh, float* __restrict__ xg,
    int* __restrict__ pool, int* __restrict__ winner, u32* __restrict__ hx2)
{
    __shared__ __align__(16) float es[4][EMBD];
    const int tid = threadIdx.x;
    const int t0  = blockIdx.x * 4;

    if (blockIdx.x == 0) {
        if (tid < 16) pool[tid] = 0;
        if (tid == 16) *winner = -1;
        if (tid < 2 * HID + 32) hx2[tid] = 0u;   // mirror slots + slack
    }

    for (int p = tid; p < 4 * EMBD; p += 256) {
        const int tt = p >> 7, k = p & 127;
        es[tt][k] = emb[(long)tok[t0 + tt] * EMBD + k];
    }
    __syncthreads();

#pragma unroll
    for (int q = 0; q < 4; ++q) {
        const int j = q * 256 + tid;
        const float4* wr = (const float4*)(Wih + (long)j * EMBD);
        float a0 = 0.f, a1 = 0.f, a2 = 0.f, a3 = 0.f;
#pragma unroll 8
        for (int k4 = 0; k4 < EMBD / 4; ++k4) {
            const float4 w  = wr[k4];
            const float4 e0 = ((const float4*)es[0])[k4];
            const float4 e1 = ((const float4*)es[1])[k4];
            const float4 e2 = ((const float4*)es[2])[k4];
            const float4 e3 = ((const float4*)es[3])[k4];
            a0 += w.x*e0.x + w.y*e0.y + w.z*e0.z + w.w*e0.w;
            a1 += w.x*e1.x + w.y*e1.y + w.z*e1.z + w.w*e1.w;
            a2 += w.x*e2.x + w.y*e2.y + w.z*e2.z + w.w*e2.w;
            a3 += w.x*e3.x + w.y*e3.y + w.z*e3.z + w.w*e3.w;
        }
        const float bb = bih[j] + bhh[j];
        xg[(long)(t0 + 0) * G4 + j] = a0 + bb;
        xg[(long)(t0 + 1) * G4 + j] = a1 + bb;
        xg[(long)(t0 + 2) * G4 + j] = a2 + bb;
        xg[(long)(t0 + 3) * G4 + j] = a3 + bb;
    }
}

// ---------------------------------------------------------------------------
// Kernel B: LSTM recurrence, NBLK=16 working blocks, target: one XCD.
// XCC id now read via the SYMBOLIC assembler name (numeric ids 20/窗口 guesses
// failed in R4/R5 — counters proved winners were cross-XCD both times).
// Registration never blocks -> no deadlock; losers exit.
//
// Exchange per step: producer packs ((s+1)<<16)|bf16(h), dual-publishes:
//   (a) sc0 store -> shared L2 (fast path, full history in hx)
//   (b) agent-relaxed -> 2-slot mirror hx2 (R3-proven fallback; slot for
//       h_{s+1} provably not overwritten until every block consumed it)
// Consumers: adaptive sc0 budget (12; drops to 1 after a fallback, restored
// on success) then mirror polling. Worst case ~= R3 protocol.
//
// Weights: 16 NAMED float4s (no array, no lambda) -> SROA keeps them in
// VGPRs. R3-R5's VGPR_Count=52 + 24.6 GB/launch scratch writes proved the
// lambda-captured array lived in scratch, on the serial critical path.
// ---------------------------------------------------------------------------
__global__ __launch_bounds__(256) void lstm_kernel(
    const float* __restrict__ Whh, const float* __restrict__ xg,
    u32* __restrict__ hx, u32* __restrict__ hx2,
    int* __restrict__ pool, int* __restrict__ winner)
{
    const int tid = threadIdx.x;

    u32 xcc;
    asm volatile("s_getreg_b32 %0, hwreg(HW_REG_XCC_ID, 0, 4)" : "=s"(xcc));
    xcc &= 15u;

    __shared__ int s_b;
    if (tid == 0) {
        int b = -1;
        const int slot = atomicAdd(&pool[xcc], 1);
        if (slot < NBLK) {
            if (slot == NBLK - 1) atomicCAS(winner, -1, (int)xcc);
            int w;
            while ((w = __hip_atomic_load(winner, __ATOMIC_RELAXED,
                                          __HIP_MEMORY_SCOPE_AGENT)) == -1)
                __builtin_amdgcn_s_sleep(8);
            if (w == (int)xcc) b = slot;
        }
        s_b = b;
    }
    __syncthreads();
    const int b = s_b;
    if (b < 0) return;                 // not part of the winning 16

    const int w   = tid >> 6;
    const int L   = tid & 63;
    const int g   = L >> 4;
    const int l15 = L & 15;
    const int hi  = l15 >> 2;
    const int q   = L & 3;
    const int row = g * HID + b * SH + w * 4 + hi;

    const float4* wsrc = (const float4*)(Whh + (long)row * HID + q * 64);
#define LOADW(J) const float4 w##J = wsrc[J];
    LOADW(0)  LOADW(1)  LOADW(2)  LOADW(3)
    LOADW(4)  LOADW(5)  LOADW(6)  LOADW(7)
    LOADW(8)  LOADW(9)  LOADW(10) LOADW(11)
    LOADW(12) LOADW(13) LOADW(14) LOADW(15)
#undef LOADW

    __shared__ __align__(16) float hlds[2][4 * QW];
    for (int i = tid; i < 4 * QW; i += 256) hlds[0][i] = 0.f;   // h_0 = 0
    __syncthreads();

    float c_reg = 0.f;
    int   kbud  = 12;                  // adaptive sc0 spin budget
    const bool leader = (g == 0) && (q == 0);
    const int  gidx   = b * SH + w * 4 + hi;
    const int  myslot = (tid >> 6) * QW + (tid & 63);
    const bool remote = (tid >> 4) != b;

    const float* xgp = xg + row;
    float xg0 = xgp[0];
    float xg1 = xgp[G4];               // may prefetch past xg end into hx: benign

#define ACC(J) { const float4 hv = *(const float4*)(hb + (J)*4); \
        p0 = __builtin_fmaf(w##J.x, hv.x, p0); \
        p1 = __builtin_fmaf(w##J.y, hv.y, p1); \
        p2 = __builtin_fmaf(w##J.z, hv.z, p2); \
        p3 = __builtin_fmaf(w##J.w, hv.w, p3); }

#define STEP(CUR, S_, XGV) { \
        const float* hb = &hlds[CUR][q * QW]; \
        float p0 = 0.f, p1 = 0.f, p2 = 0.f, p3 = 0.f; \
        ACC(0)  ACC(1)  ACC(2)  ACC(3)  ACC(4)  ACC(5)  ACC(6)  ACC(7) \
        ACC(8)  ACC(9)  ACC(10) ACC(11) ACC(12) ACC(13) ACC(14) ACC(15) \
        float p = (p0 + p1) + (p2 + p3); \
        p += __shfl_xor(p, 1, 64); \
        p += __shfl_xor(p, 2, 64); \
        const float pre = p + (XGV); \
        const float vf = __shfl(pre, 16 + l15, 64); \
        const float vg = __shfl(pre, 32 + l15, 64); \
        const float vo = __shfl(pre, 48 + l15, 64); \
        if (leader) { \
            const float i_ = sigf(pre); \
            const float f_ = sigf(vf); \
            const float g_ = tanhf_fast(vg); \
            const float o_ = sigf(vo); \
            c_reg = f_ * c_reg + i_ * g_; \
            const float hn = o_ * tanhf_fast(c_reg); \
            const u32 hb32 = __float_as_uint(hn); \
            const u32 rb   = (hb32 + 0x7FFFu + ((hb32 >> 16) & 1u)) >> 16; \
            const u32 word = ((u32)((S_) + 1) << 16) | rb; \
            store_u32_sc0(&hx[(long)((S_) + 1) * HID + gidx], word); \
            __hip_atomic_store(&hx2[(((S_) + 1) & 1) * HID + gidx], word, \
                               __ATOMIC_RELAXED, __HIP_MEMORY_SCOPE_AGENT); \
            hlds[(CUR) ^ 1][(gidx >> 6) * QW + (gidx & 63)] = \
                __uint_as_float(rb << 16); \
        } \
        if (remote) { \
            const u32 want = (u32)((S_) + 1) << 16; \
            u32* wp  = &hx[(long)((S_) + 1) * HID + tid]; \
            u32* wp2 = &hx2[(((S_) + 1) & 1) * HID + tid]; \
            u32 u; bool fast = false; \
            for (int it = 0; it < kbud; ++it) { \
                u = load_u32_sc0(wp); \
                if ((u & 0xFFFF0000u) == want) { fast = true; break; } \
            } \
            if (!fast) { \
                do { u = __hip_atomic_load(wp2, __ATOMIC_RELAXED, \
                                           __HIP_MEMORY_SCOPE_AGENT); } \
                while ((u & 0xFFFF0000u) != want); \
                kbud = 1; \
            } else { \
                kbud = 12; \
            } \
            hlds[(CUR) ^ 1][myslot] = __uint_as_float(u << 16); \
        } \
        __syncthreads(); }

    for (int s = 0; s < TT; s += 2) {
        const float xgn0 = xgp[(long)(s + 2) * G4];
        STEP(0, s, xg0)
        const float xgn1 = xgp[(long)(s + 3) * G4];
        STEP(1, s + 1, xg1)
        xg0 = xgn0; xg1 = xgn1;
    }
#undef STEP
#undef ACC
}

// ---------------------------------------------------------------------------
// Kernel C: tag logits + log_softmax; unpacks bf16 h from tagged words.
// ---------------------------------------------------------------------------
__global__ __launch_bounds__(64) void out_kernel(
    const u32* __restrict__ hx, const float* __restrict__ Wout,
    const float* __restrict__ bout, float* __restrict__ out)
{
    const int t   = blockIdx.x;
    const int tid = threadIdx.x;
    __shared__ __align__(16) float hs[HID];
    __shared__ float lg[NTAGS];

    const uint4 uu = ((const uint4*)(hx + (long)(t + 1) * HID))[tid];
    hs[tid * 4 + 0] = __uint_as_float(uu.x << 16);
    hs[tid * 4 + 1] = __uint_as_float(uu.y << 16);
    hs[tid * 4 + 2] = __uint_as_float(uu.z << 16);
    hs[tid * 4 + 3] = __uint_as_float(uu.w << 16);
    __syncthreads();

    if (tid < NTAGS) {
        const float4* wr = (const float4*)(Wout + (long)tid * HID);
        float p = 0.f;
#pragma unroll 8
        for (int qq = 0; qq < HID / 4; ++qq) {
            const float4 w = wr[qq];
            const float4 h = ((const float4*)hs)[qq];
            p += w.x*h.x + w.y*h.y + w.z*h.z + w.w*h.w;
        }
        lg[tid] = p + bout[tid];
    }
    __syncthreads();

    if (tid < NTAGS) {
        float m = -1e30f;
        for (int gg = 0; gg < NTAGS; ++gg) m = fmaxf(m, lg[gg]);
        float ss = 0.f;
        for (int gg = 0; gg < NTAGS; ++gg) ss += __expf(lg[gg] - m);
        out[(long)t * NTAGS + tid] = lg[tid] - (m + __logf(ss));
    }
}

// ---------------------------------------------------------------------------
// ws layout (total 41,948,424 B — R4/R5-proven to fit):
//   xg     : 33,554,432 B
//   hx     :  8,389,632 B   (8193 * 256 tagged words)
//   hx2    :      2,176 B   (2 * 256 mirror + slack)
//   pool   :         64 B
//   winner :          4 B
// ---------------------------------------------------------------------------
extern "C" void kernel_launch(void* const* d_in, const int* in_sizes, int n_in,
                              void* d_out, int out_size, void* d_ws, size_t ws_size,
                              hipStream_t stream)
{
    const int*   tok  = (const int*)  d_in[0];
    const float* emb  = (const float*)d_in[1];
    const float* Wih  = (const float*)d_in[2];
    const float* Whh  = (const float*)d_in[3];
    const float* bih  = (const float*)d_in[4];
    const float* bhh  = (const float*)d_in[5];
    const float* Wout = (const float*)d_in[6];
    const float* bout = (const float*)d_in[7];
    float* out = (float*)d_out;

    char* ws = (char*)d_ws;
    float* xg     = (float*)(ws);
    u32*   hx     = (u32*)  (ws + 33554432UL);
    u32*   hx2    = (u32*)  (ws + 33554432UL + 8389632UL);
    int*   pool   = (int*)  (ws + 33554432UL + 8389632UL + 2176UL);
    int*   winner = (int*)  (ws + 33554432UL + 8389632UL + 2176UL + 64UL);

    xg_kernel  <<<TT / 4,   256, 0, stream>>>(tok, emb, Wih, bih, bhh, xg,
                                              pool, winner, hx2);
    lstm_kernel<<<REG_GRID, 256, 0, stream>>>(Whh, xg, hx, hx2, pool, winner);
    out_kernel <<<TT,       64,  0, stream>>>(hx, Wout, bout, out);
}